// Round 5
// baseline (484.160 us; speedup 1.0000x reference)
//
#include <hip/hip_runtime.h>

#define VOCAB 8192
#define CTX 4
#define OBLK 16                      // fc_w rows (output columns) per workgroup
#define ROWSTRIDE (CTX * VOCAB)      // 32768 floats per fc_w row

// Barrier-free direct gather (no LDS). Thread t == batch t; WG owns rows
// o0..o0+15 and all 1024 batches. All 16 waves traverse the same 32 KB
// row-region (o,i) in the same program order, so the ~1.9x line reuse
// (1024 scattered 4B gathers over 512 x 64B lines per region) is served by
// L1/L2; HBM sees each needed line once, and the ~14% of lines no context
// index touches are never fetched at all. No staging writes, no barriers,
// no convoy: waves run free, 32 waves/CU hide gather latency.
__global__ __launch_bounds__(1024, 8) void cbow_kernel(
    const int*   __restrict__ contexts,   // [1024, 4] int32
    const float* __restrict__ fc_w,       // [8192, 32768] row-major f32
    const float* __restrict__ fc_b,       // [8192] f32
    float*       __restrict__ out)        // [1024, 8192] f32
{
    const int t  = threadIdx.x;           // == batch index b
    const int o0 = blockIdx.x * OBLK;

    // This thread's 4 context indices -> column offsets within a 32768-float row.
    const int4 cv = ((const int4*)contexts)[t];
    const int col0 = 0 * VOCAB + cv.x;
    const int col1 = 1 * VOCAB + cv.y;
    const int col2 = 2 * VOCAB + cv.z;
    const int col3 = 3 * VOCAB + cv.w;

    // Accumulators init with bias (WG-uniform -> scalar loads).
    float acc[OBLK];
#pragma unroll
    for (int j = 0; j < OBLK; ++j) acc[j] = fc_b[o0 + j];

    // 64 independent scattered loads per thread, fully unrolled (static acc
    // indices, rule #20). Row-major traversal keeps the whole WG inside one
    // contiguous 128 KB row at a time -> tight cache window, sequential DRAM.
#pragma unroll
    for (int j = 0; j < OBLK; ++j) {
        const float* row = fc_w + (size_t)(o0 + j) * ROWSTRIDE;
        acc[j] += (row[col0] + row[col1]) + (row[col2] + row[col3]);
    }

    // Thread t writes out[t, o0..o0+15] = 64 contiguous bytes (full line).
    float4* op = (float4*)(out + (size_t)t * VOCAB + o0);
#pragma unroll
    for (int j = 0; j < OBLK / 4; ++j) {
        float4 v;
        v.x = acc[4 * j + 0];
        v.y = acc[4 * j + 1];
        v.z = acc[4 * j + 2];
        v.w = acc[4 * j + 3];
        op[j] = v;
    }
}

extern "C" void kernel_launch(void* const* d_in, const int* in_sizes, int n_in,
                              void* d_out, int out_size, void* d_ws, size_t ws_size,
                              hipStream_t stream) {
    const int*   contexts = (const int*)d_in[0];
    const float* fc_w     = (const float*)d_in[1];
    const float* fc_b     = (const float*)d_in[2];
    float*       out      = (float*)d_out;

    dim3 grid(VOCAB / OBLK);   // 512 workgroups, 2 resident per CU
    dim3 block(1024);
    cbow_kernel<<<grid, block, 0, stream>>>(contexts, fc_w, fc_b, out);
}

// Round 7
// 205.806 us; speedup vs baseline: 2.3525x; 2.3525x over previous
//
#include <hip/hip_runtime.h>

#define VOCAB 8192
#define CTX 4
#define OBLK 16                  // fc_w rows (output columns) per workgroup
#define NCHUNK (OBLK * CTX)      // 64 chunks of VOCAB floats each

// Streaming + LDS gather via global_load_lds DMA, double-buffered 2 x 32 KB,
// 2 WGs/CU. Two barriers per chunk restore the WAR guard R6 lost:
//   gather k | B1(lgkm: all gathers of k retired -> slot free)
//   DMA k+2 into slot k&1 | B2(vmcnt(2): chunk k+1 resident)
// vmcnt ledger at B2: outstanding = {k+1: 2 oldest, k+2: 2 newest} -> wait(2)
// retires exactly chunk k+1. vmcnt is never drained to 0 in the loop.
__global__ __launch_bounds__(1024) void cbow_kernel(
    const int*   __restrict__ contexts,   // [1024, 4] int32
    const float* __restrict__ fc_w,       // [8192, 32768] row-major f32
    const float* __restrict__ fc_b,       // [8192] f32
    float*       __restrict__ out)        // [1024, 8192] f32
{
    __shared__ float lds[2][VOCAB];       // 64 KB -> 2 WGs/CU, 32 waves/CU

    const int t  = threadIdx.x;           // == batch index b
    const int w  = t >> 6;                // wave id (wave-uniform)
    const int l  = t & 63;                // lane
    const int o0 = blockIdx.x * OBLK;
    const size_t base = (size_t)o0 * (CTX * VOCAB);  // this WG's contiguous slice

    const int4 cv = ((const int4*)contexts)[t];
    const int cc[4] = {cv.x, cv.y, cv.z, cv.w};
    // Materialize ctx indices NOW (forces the one vmem wait while nothing else
    // is in flight; keeps the compiler from placing vmem waits in the loop).
    asm volatile("" :: "v"(cc[0]), "v"(cc[1]), "v"(cc[2]), "v"(cc[3]));

    float acc[OBLK];
#pragma unroll
    for (int j = 0; j < OBLK; ++j) acc[j] = fc_b[o0 + j];

    // DMA writes lane l's 16 B at (wave-uniform LDS base) + l*16, so the
    // per-lane global source must advance by l*4 floats to match.
    const int dmaoff = w * 512 + l * 4;

#define DMA_CHUNK(kk, s) do {                                                   \
    const float* g_ = fc_w + base + (size_t)(kk) * VOCAB + dmaoff;              \
    __builtin_amdgcn_global_load_lds(                                           \
        (const __attribute__((address_space(1))) void*)g_,                      \
        (__attribute__((address_space(3))) void*)&lds[s][w * 512], 16, 0, 0);   \
    __builtin_amdgcn_global_load_lds(                                           \
        (const __attribute__((address_space(1))) void*)(g_ + 256),              \
        (__attribute__((address_space(3))) void*)&lds[s][w * 512 + 256], 16, 0, 0); \
} while (0)

    // Prologue: chunks 0,1 in flight; wait only chunk 0 (vmcnt(2)) then barrier.
    DMA_CHUNK(0, 0);
    DMA_CHUNK(1, 1);
    asm volatile("s_waitcnt vmcnt(2)\n\ts_barrier" ::: "memory");

    // Fully unrolled: acc/cc indices and slots are compile-time.
#pragma unroll
    for (int k = 0; k < NCHUNK; ++k) {
        // Gather chunk k (row k>>2, ctx position k&3): one random ds_read_b32.
        acc[k >> 2] += lds[k & 1][cc[k & 3]];

        if (k == NCHUNK - 1) break;       // last chunk: no more sync needed

        // B1: all waves' gathers of chunk k retired -> slot k&1 reusable.
        asm volatile("s_waitcnt lgkmcnt(0)\n\ts_barrier" ::: "memory");

        if (k + 2 < NCHUNK) {
            DMA_CHUNK(k + 2, k & 1);      // overwrite just-freed slot
            // B2: chunk k+1 resident (my 2 oldest DMAs retired + all arrived).
            asm volatile("s_waitcnt vmcnt(2)\n\ts_barrier" ::: "memory");
        } else {
            // Tail (k = NCHUNK-2): nothing left to prefetch; chunk 63 resident.
            asm volatile("s_waitcnt vmcnt(0)\n\ts_barrier" ::: "memory");
        }
    }
#undef DMA_CHUNK

    // Epilogue: thread t writes out[t, o0..o0+15] = 64 contiguous bytes
    // (one full cache line, fully written).
    float4* op = (float4*)(out + (size_t)t * VOCAB + o0);
#pragma unroll
    for (int j = 0; j < OBLK / 4; ++j) {
        float4 v;
        v.x = acc[4 * j + 0];
        v.y = acc[4 * j + 1];
        v.z = acc[4 * j + 2];
        v.w = acc[4 * j + 3];
        op[j] = v;
    }
}

extern "C" void kernel_launch(void* const* d_in, const int* in_sizes, int n_in,
                              void* d_out, int out_size, void* d_ws, size_t ws_size,
                              hipStream_t stream) {
    const int*   contexts = (const int*)d_in[0];
    const float* fc_w     = (const float*)d_in[1];
    const float* fc_b     = (const float*)d_in[2];
    float*       out      = (float*)d_out;

    dim3 grid(VOCAB / OBLK);   // 512 workgroups, 2 resident per CU
    dim3 block(1024);
    cbow_kernel<<<grid, block, 0, stream>>>(contexts, fc_w, fc_b, out);
}

// Round 8
// 203.130 us; speedup vs baseline: 2.3835x; 1.0132x over previous
//
#include <hip/hip_runtime.h>

#define VOCAB 8192
#define CTX 4
#define OBLK 16                  // fc_w rows (output columns) per workgroup
#define NCHUNK (OBLK * CTX)      // 64 chunks of VOCAB floats each

// R3 structure (best known: 201.6 us): double-buffered 2x32 KB LDS, VGPR-
// staged stream, ONE raw lgkm-only barrier per chunk (vmcnt stays counted).
// This round: (1) 3-chunk register slack (issue k+3, write k+1, gather k);
// (2) coalesced epilogue — transpose acc through the dead LDS buffer so
// each wave store covers 16 fully-written 64B lines instead of 64x16B
// scattered partials.
__global__ __launch_bounds__(1024) void cbow_kernel(
    const int*   __restrict__ contexts,   // [1024, 4] int32
    const float* __restrict__ fc_w,       // [8192, 32768] row-major f32
    const float* __restrict__ fc_b,       // [8192] f32
    float*       __restrict__ out)        // [1024, 8192] f32
{
    __shared__ float lds[2][VOCAB];       // 64 KB -> 2 WGs/CU, 32 waves/CU

    const int t  = threadIdx.x;           // == batch index b
    const int o0 = blockIdx.x * OBLK;
    const size_t base = (size_t)o0 * (CTX * VOCAB);  // this WG's contiguous slice

    const int4 cv = ((const int4*)contexts)[t];
    const int cc[4] = {cv.x, cv.y, cv.z, cv.w};

    float acc[OBLK];
#pragma unroll
    for (int j = 0; j < OBLK; ++j) acc[j] = fc_b[o0 + j];

    // Prologue: chunk 0 -> LDS[0]; chunks 1,2 -> register stages.
    {
        const float4* s0 = (const float4*)(fc_w + base);
        float4 a = s0[t], b = s0[1024 + t];
        float4* dst = (float4*)lds[0];
        dst[t] = a; dst[1024 + t] = b;
    }
    const float4* s1p = (const float4*)(fc_w + base + VOCAB);
    float4 ra1 = s1p[t], rb1 = s1p[1024 + t];          // chunk k+1 (to write next)
    const float4* s2p = (const float4*)(fc_w + base + 2 * VOCAB);
    float4 ra2 = s2p[t], rb2 = s2p[1024 + t];          // chunk k+2
    asm volatile("s_waitcnt lgkmcnt(0)\n\ts_barrier" ::: "memory");

    // Main loop, fully unrolled (static acc/cc indices, compile-time parity).
    // WAR: ds_write of chunk k+1 hits the slot whose chunk k-1 gathers all
    // retired before the barrier ending iter k-1. vmcnt ledger at ds_write:
    // outstanding = {k+1:2 oldest, k+2:2, k+3:2 newest} -> compiler waits
    // vmcnt(4); the 4 newest loads ride across the barrier.
#pragma unroll
    for (int k = 0; k < NCHUNK; ++k) {
        float4 na, nb;
        if (k + 3 < NCHUNK) {             // issue loads for chunk k+3 FIRST
            const float4* src = (const float4*)(fc_w + base + (size_t)(k + 3) * VOCAB);
            na = src[t]; nb = src[1024 + t];
        }
        if (k + 1 < NCHUNK) {             // write chunk k+1 (loaded 2 iters ago)
            float4* dst = (float4*)lds[(k + 1) & 1];
            dst[t] = ra1; dst[1024 + t] = rb1;
        }
        // Gather chunk k (row k>>2, ctx position k&3): one random ds_read_b32.
        acc[k >> 2] += lds[k & 1][cc[k & 3]];

        ra1 = ra2; rb1 = rb2;             // rotate register stages
        ra2 = na;  rb2 = nb;

        asm volatile("s_waitcnt lgkmcnt(0)\n\ts_barrier" ::: "memory");
    }
    // (last barrier above also guards LDS reuse by the epilogue)

    // ---- Coalesced epilogue via LDS transpose -------------------------------
    // Element (b=t, col j) lives at word t*16 + ((j/4 + t)&3)*4 + (j%4)
    // (quad-group rotated by t -> conflict-free-ish b128 phases both sides).
    float* lf = &lds[0][0];               // 64 KB flat, loop data dead
#pragma unroll
    for (int m = 0; m < 4; ++m) {
        float4 v;
        v.x = acc[4 * m + 0]; v.y = acc[4 * m + 1];
        v.z = acc[4 * m + 2]; v.w = acc[4 * m + 3];
        *(float4*)(lf + t * 16 + (((m + t) & 3) << 2)) = v;
    }
    asm volatile("s_waitcnt lgkmcnt(0)\n\ts_barrier" ::: "memory");
    // Reader: flat id f = m*1024 + t -> row r=f>>2, quad q=f&3. Consecutive
    // lanes cover consecutive 16B of out -> 4 lanes fill one 64B line fully;
    // one wave store = 16 complete lines.
#pragma unroll
    for (int m = 0; m < 4; ++m) {
        const int f = m * 1024 + t;
        const int r = f >> 2, q = f & 3;
        float4 v = *(const float4*)(lf + r * 16 + (((q + r) & 3) << 2));
        *(float4*)(out + (size_t)r * VOCAB + o0 + q * 4) = v;
    }
}

extern "C" void kernel_launch(void* const* d_in, const int* in_sizes, int n_in,
                              void* d_out, int out_size, void* d_ws, size_t ws_size,
                              hipStream_t stream) {
    const int*   contexts = (const int*)d_in[0];
    const float* fc_w     = (const float*)d_in[1];
    const float* fc_b     = (const float*)d_in[2];
    float*       out      = (float*)d_out;

    dim3 grid(VOCAB / OBLK);   // 512 workgroups, 2 resident per CU
    dim3 block(1024);
    cbow_kernel<<<grid, block, 0, stream>>>(contexts, fc_w, fc_b, out);
}